// Round 2
// baseline (717.789 us; speedup 1.0000x reference)
//
#include <hip/hip_runtime.h>
#include <math.h>

#define BATCH     8
#define SEQ       512
#define VOCAB     32000
#define PADCOLS   31488.0f        // V - S identical NEG_BIG columns
#define NEG_BIG   (-1000000000.0f)
#define NUM_ITERS 20

// ---------------------------------------------------------------------------
// Kernel 1: ce[row] = logsumexp_V(pred[row,:]) - pred[row, tgt[row]]
// One block per row (4096 rows). Streaming online-LSE, float4 loads,
// 4 independent accumulator pairs for ILP (no serial exp chain, no branch).
// ---------------------------------------------------------------------------
__global__ __launch_bounds__(256) void ce_kernel(const float* __restrict__ pred,
                                                 const int*   __restrict__ tgt,
                                                 float*       __restrict__ ce) {
    const int row = blockIdx.x;                       // b*SEQ + s
    const float* __restrict__ p = pred + (size_t)row * VOCAB;
    const int tid = threadIdx.x;

    // 4 independent online-LSE accumulators (one per float4 component)
    float m0 = -INFINITY, m1 = -INFINITY, m2 = -INFINITY, m3 = -INFINITY;
    float s0 = 0.0f, s1 = 0.0f, s2 = 0.0f, s3 = 0.0f;

    const float4* __restrict__ p4 = (const float4*)p;
    for (int i = tid; i < VOCAB / 4; i += 256) {
        float4 v = p4[i];
        float n0 = fmaxf(m0, v.x); s0 = s0 * __expf(m0 - n0) + __expf(v.x - n0); m0 = n0;
        float n1 = fmaxf(m1, v.y); s1 = s1 * __expf(m1 - n1) + __expf(v.y - n1); m1 = n1;
        float n2 = fmaxf(m2, v.z); s2 = s2 * __expf(m2 - n2) + __expf(v.z - n2); m2 = n2;
        float n3 = fmaxf(m3, v.w); s3 = s3 * __expf(m3 - n3) + __expf(v.w - n3); m3 = n3;
    }

    // merge the 4 accumulators
    float m = fmaxf(fmaxf(m0, m1), fmaxf(m2, m3));
    float s = s0 * __expf(m0 - m) + s1 * __expf(m1 - m)
            + s2 * __expf(m2 - m) + s3 * __expf(m3 - m);

    // wave (64-lane) butterfly reduce of (m, s) pairs
    #pragma unroll
    for (int off = 1; off < 64; off <<= 1) {
        float mo = __shfl_xor(m, off);
        float so = __shfl_xor(s, off);
        float mn = fmaxf(m, mo);
        s = s * __expf(m - mn) + so * __expf(mo - mn);
        m = mn;
    }

    // combine 4 waves via LDS
    __shared__ float sm[4], ss[4];
    if ((tid & 63) == 0) { sm[tid >> 6] = m; ss[tid >> 6] = s; }
    __syncthreads();
    if (tid == 0) {
        float M = sm[0], S = ss[0];
        #pragma unroll
        for (int w = 1; w < 4; ++w) {
            float mo = sm[w], so = ss[w];
            float mn = fmaxf(M, mo);
            S = S * __expf(M - mn) + so * __expf(mo - mn);
            M = mn;
        }
        float lse = M + logf(S);
        ce[row] = lse - p[tgt[row]];
    }
}

// ---------------------------------------------------------------------------
// Kernel 2: structurally-reduced Sinkhorn + loss.
// cost[b,s,:] == { u[b,s] at col 0, r[b,s] at the 31488 pad cols }.
// Both logsumexp normalizations preserve this 2-value structure exactly:
//   axis-2 lse = m + log(exp(u-m) + 31488*exp(r-m))
//   axis-1 lse = per-batch lse over S of u (resp. r)
// One block of 512 threads; wave w == batch b; each lane owns 8 s-positions.
// ---------------------------------------------------------------------------
__global__ __launch_bounds__(512) void sinkhorn_kernel(const float* __restrict__ ce,
                                                       float*       __restrict__ out) {
    const int tid  = threadIdx.x;
    const int b    = tid >> 6;     // wave index == batch index
    const int lane = tid & 63;

    float u[8], r[8], c[8];
    #pragma unroll
    for (int j = 0; j < 8; ++j) {
        c[j] = ce[b * SEQ + j * 64 + lane];   // coalesced
        u[j] = -c[j];                          // cost col 0 = -ce / TAU, TAU=1
        r[j] = NEG_BIG;                        // pad columns
    }

    for (int it = 0; it < NUM_ITERS; ++it) {
        // ---- axis-2 normalize (closed form over the 31489 columns) ----
        #pragma unroll
        for (int j = 0; j < 8; ++j) {
            float m   = fmaxf(u[j], r[j]);
            float sum = expf(u[j] - m) + PADCOLS * expf(r[j] - m);
            float L2  = m + logf(sum);
            u[j] -= L2;
            r[j] -= L2;
        }
        // ---- axis-1 normalize: lse over S=512 of u (wave-local, shfl only) ----
        {
            float m = u[0];
            #pragma unroll
            for (int j = 1; j < 8; ++j) m = fmaxf(m, u[j]);
            #pragma unroll
            for (int off = 1; off < 64; off <<= 1) m = fmaxf(m, __shfl_xor(m, off));
            float s = 0.0f;
            #pragma unroll
            for (int j = 0; j < 8; ++j) s += expf(u[j] - m);
            #pragma unroll
            for (int off = 1; off < 64; off <<= 1) s += __shfl_xor(s, off);
            float L1 = m + logf(s);
            #pragma unroll
            for (int j = 0; j < 8; ++j) u[j] -= L1;
        }
        // ---- same for r ----
        {
            float m = r[0];
            #pragma unroll
            for (int j = 1; j < 8; ++j) m = fmaxf(m, r[j]);
            #pragma unroll
            for (int off = 1; off < 64; off <<= 1) m = fmaxf(m, __shfl_xor(m, off));
            float s = 0.0f;
            #pragma unroll
            for (int j = 0; j < 8; ++j) s += expf(r[j] - m);
            #pragma unroll
            for (int off = 1; off < 64; off <<= 1) s += __shfl_xor(s, off);
            float L1 = m + logf(s);
            #pragma unroll
            for (int j = 0; j < 8; ++j) r[j] -= L1;
        }
    }

    // ---- loss_b = sum_s (exp(u) + 31488*exp(r)) * ce ----
    float acc = 0.0f;
    #pragma unroll
    for (int j = 0; j < 8; ++j)
        acc += (expf(u[j]) + PADCOLS * expf(r[j])) * c[j];
    #pragma unroll
    for (int off = 1; off < 64; off <<= 1) acc += __shfl_xor(acc, off);

    __shared__ float part[8];
    if (lane == 0) part[b] = acc;
    __syncthreads();
    if (tid == 0) {
        float t = 0.0f;
        #pragma unroll
        for (int w = 0; w < 8; ++w) t += part[w];
        out[0] = t / (float)BATCH;             // mean over batch
    }
}

// ---------------------------------------------------------------------------
extern "C" void kernel_launch(void* const* d_in, const int* in_sizes, int n_in,
                              void* d_out, int out_size, void* d_ws, size_t ws_size,
                              hipStream_t stream) {
    const float* pred = (const float*)d_in[0];   // (8,512,32000) f32
    const int*   tgt  = (const int*)d_in[1];     // (8,512) int
    float* out = (float*)d_out;                  // scalar f32
    float* ce  = (float*)d_ws;                   // 4096 f32 scratch

    ce_kernel<<<BATCH * SEQ, 256, 0, stream>>>(pred, tgt, ce);
    sinkhorn_kernel<<<1, 512, 0, stream>>>(ce, out);
}